// Round 1
// baseline (3337.491 us; speedup 1.0000x reference)
//
#include <hip/hip_runtime.h>
#include <hip/hip_fp16.h>

#define S 31
#define D 14
#define H 50
#define MH 6
#define NB 16384
#define NITER 48
#define LAMR 1e-4f

// ws float-index layout
#define WS_D2   0      // 48 floats: global sum ||F-X||^2 per iter
#define WS_F2   64     // 48 floats: global sum ||F||^2 per iter
#define WS_WHP  128    // 50x16 padded Wh
#define WS_WXP  928    // 50x16 padded Wx
#define WS_WOT  1728   // 50x16 padded Wo^T (wot[h*16+d] = Wo[d][h])
#define WS_BHX  2528   // 64: bh+bx
#define WS_BO   2592   // 16: bo
#define WS_OUTK 4096   // 48 * NB floats: dot(Wf, F_k) per element

#ifndef __has_builtin
#define __has_builtin(x) 0
#endif
#if __has_builtin(__builtin_amdgcn_rcpf)
#define FRCP(x) __builtin_amdgcn_rcpf(x)
#else
#define FRCP(x) (1.0f/(x))
#endif

__device__ __forceinline__ float tfast(float x){
  float e = __expf(x + x);
  return 1.f - 2.f * FRCP(e + 1.f);
}

__device__ __forceinline__ float half_red(float v){
  v += __shfl_xor(v, 1, 64);
  v += __shfl_xor(v, 2, 64);
  v += __shfl_xor(v, 4, 64);
  v += __shfl_xor(v, 8, 64);
  v += __shfl_xor(v, 16, 64);
  return v;   // sum over the 32-lane half; all lanes get it
}

__global__ void prep_kernel(const float* __restrict__ Wh, const float* __restrict__ bh,
                            const float* __restrict__ Wx, const float* __restrict__ bx,
                            const float* __restrict__ Wo, const float* __restrict__ bo,
                            float* __restrict__ ws){
  int t = threadIdx.x;                       // 1 block x 256
  for (int i=t;i<128;i+=256) ws[i]=0.f;      // zero norm accumulators
  for (int i=t;i<800;i+=256){
    int h=i>>4, d=i&15;
    ws[WS_WHP+i] = (d<D)? Wh[h*D+d] : 0.f;
    ws[WS_WXP+i] = (d<D)? Wx[h*D+d] : 0.f;
    ws[WS_WOT+i] = (d<D)? Wo[d*H+h] : 0.f;
  }
  for (int i=t;i<64;i+=256) ws[WS_BHX+i] = (i<H)? bh[i]+bx[i] : 0.f;
  for (int i=t;i<16;i+=256) ws[WS_BO+i]  = (i<D)? bo[i] : 0.f;
}

// f-eval: fv = tanh( tanh(hx + xv@Wx^T) @ Wo^T + bo ).  xv,fv in regs.
#define FEVAL() do{ \
  float tac[D]; \
  _Pragma("unroll") for (int d_=0; d_<D; ++d_) tac[d_]=bop[d_]; \
  _Pragma("unroll 2") \
  for (int h_=0; h_<H; ++h_){ \
    const float* wxr = wxp + h_*16; \
    const float* wor = wot + h_*16; \
    float a0 = hxr[h_], a1 = 0.f; \
    _Pragma("unroll") for (int d_=0; d_<D; d_+=2){ a0 += xv[d_]*wxr[d_]; a1 += xv[d_+1]*wxr[d_+1]; } \
    float th = tfast(a0+a1); \
    _Pragma("unroll") for (int d_=0; d_<D; ++d_) tac[d_] += th*wor[d_]; \
  } \
  _Pragma("unroll") for (int d_=0; d_<D; ++d_) fv[d_] = tfast(tac[d_]); \
}while(0)

// store history slot r (F=fv, G=gv, fp16-packed) and refresh GG row/col r
#define UPD(r) do{ \
  _Pragma("unroll") for (int dd_=0;dd_<7;++dd_){ \
    Fh[r][dd_]=__floats2half2_rn(fv[2*dd_],fv[2*dd_+1]); \
    Gh[r][dd_]=__floats2half2_rn(gv[2*dd_],gv[2*dd_+1]); } \
  _Pragma("unroll") for (int j_=0;j_<MH;++j_){ \
    float dl=0.f; \
    _Pragma("unroll") for (int dd_=0;dd_<7;++dd_){ \
      float2 g2=__half22float2(Gh[j_][dd_]); \
      dl += gv[2*dd_]*g2.x + gv[2*dd_+1]*g2.y; } \
    if (!act) dl=0.f; \
    dl = half_red(dl); \
    GG[(r)*6+j_]=dl; GG[j_*6+(r)]=dl; \
  } \
}while(0)

// one Anderson iteration, k=kk (runtime, wave-uniform), ring slot r (compile-time)
#define ITER(kk, r) do{ \
  float A[36], y[6]; \
  _Pragma("unroll") for (int i_=0;i_<6;++i_){ \
    _Pragma("unroll") for (int j_=0;j_<6;++j_){ \
      float v_ = GG[i_*6+j_]; \
      if (i_==j_) v_ = (i_ < (kk)) ? (v_ + LAMR) : 1e30f; \
      else        v_ = ((i_ < (kk)) && (j_ < (kk))) ? v_ : 0.f; \
      A[i_*6+j_]=v_; } \
    y[i_]=1.f; } \
  /* GE, no pivoting (SPD + big-diag pads) */ \
  _Pragma("unroll") for (int p_=0;p_<6;++p_){ \
    float inv_ = FRCP(A[p_*6+p_]); \
    A[p_*6+p_]=inv_; \
    _Pragma("unroll") for (int i2_=p_+1;i2_<6;++i2_){ \
      float m_ = A[i2_*6+p_]*inv_; \
      _Pragma("unroll") for (int j2_=p_+1;j2_<6;++j2_) A[i2_*6+j2_] -= m_*A[p_*6+j2_]; \
      y[i2_] -= m_*y[p_]; } } \
  _Pragma("unroll") for (int p_=5;p_>=0;--p_){ \
    float ac_=y[p_]; \
    _Pragma("unroll") for (int j2_=p_+1;j2_<6;++j2_) ac_ -= A[p_*6+j2_]*y[j2_]; \
    y[p_]=ac_*A[p_*6+p_]; } \
  float isum = FRCP(y[0]+y[1]+y[2]+y[3]+y[4]+y[5]); \
  /* Xk = sum_j alpha_j F_j */ \
  _Pragma("unroll") for (int d_=0;d_<D;++d_) xv[d_]=0.f; \
  _Pragma("unroll") for (int j_=0;j_<6;++j_){ \
    float aj_ = y[j_]*isum; \
    _Pragma("unroll") for (int dd_=0;dd_<7;++dd_){ \
      float2 fw_=__half22float2(Fh[j_][dd_]); \
      xv[2*dd_]   += aj_*fw_.x; \
      xv[2*dd_+1] += aj_*fw_.y; } } \
  FEVAL(); \
  float fk2=0.f, d2l=0.f; \
  _Pragma("unroll") for (int d_=0;d_<D;++d_){ gv[d_]=fv[d_]-xv[d_]; fk2 += fv[d_]*fv[d_]; d2l += gv[d_]*gv[d_]; } \
  if (!act){ fk2=0.f; d2l=0.f; } \
  UPD(r); \
  float d2r = half_red(d2l); \
  float f2r = half_red(fk2); \
  float d2w = d2r + __shfl_xor(d2r, 32, 64); \
  float f2w = f2r + __shfl_xor(f2r, 32, 64); \
  if (lane==0){ atomicAdd(&d2p[(kk)-2], d2w); atomicAdd(&f2p[(kk)-2], f2w); } \
  float po=0.f; \
  if (act){ const float* wfr = wf + s*D; \
    _Pragma("unroll") for (int d_=0;d_<D;++d_) po += fv[d_]*wfr[d_]; } \
  po = half_red(po); \
  if (s==0) outk[((kk)-2)*NB + elem] = po; \
}while(0)

__global__ __launch_bounds__(64, 2)
void solver_kernel(const float* __restrict__ x, const float* __restrict__ wf,
                   const float* __restrict__ whp, const float* __restrict__ wxp,
                   const float* __restrict__ wot, const float* __restrict__ bhx,
                   const float* __restrict__ bop,
                   float* __restrict__ outk, float* __restrict__ d2p, float* __restrict__ f2p){
  const int lane = threadIdx.x;
  const int half = lane >> 5;
  const int s    = lane & 31;
  const int elem = blockIdx.x*2 + half;
  const bool act = (s < S);

  __shared__ float hx[2][32][51];   // odd stride -> conflict-free across lanes

  { // prologue: hx[s][h] = x_s . Wh_h + bh_h + bx_h
    float xd[D];
#pragma unroll
    for (int d=0; d<D; ++d) xd[d]=0.f;
    if (act){
      const float* xr = x + ((size_t)elem*S + s)*D;
#pragma unroll
      for (int d=0; d<D; ++d) xd[d]=xr[d];
    }
    for (int h=0; h<H; ++h){
      float a0 = bhx[h], a1 = 0.f;
#pragma unroll
      for (int d=0; d<D; d+=2){ a0 += xd[d]*whp[h*16+d]; a1 += xd[d+1]*whp[h*16+d+1]; }
      hx[half][s][h] = a0+a1;
    }
  }
  const float* hxr = &hx[half][s][0];

  __half2 Fh[MH][7], Gh[MH][7];
#pragma unroll
  for (int j=0;j<MH;++j)
#pragma unroll
    for (int dd=0;dd<7;++dd){ Fh[j][dd]=__floats2half2_rn(0.f,0.f); Gh[j][dd]=__floats2half2_rn(0.f,0.f); }
  float GG[36];
#pragma unroll
  for (int i=0;i<36;++i) GG[i]=0.f;

  float xv[D], fv[D], gv[D];

  // init: X0=0, F0=f(0); slot0: F=F0, G=F0
#pragma unroll
  for (int d=0;d<D;++d) xv[d]=0.f;
  FEVAL();
#pragma unroll
  for (int d=0;d<D;++d) gv[d]=fv[d];
  UPD(0);
  // X1=F0, F1=f(F0); slot1
#pragma unroll
  for (int d=0;d<D;++d) xv[d]=fv[d];
  FEVAL();
#pragma unroll
  for (int d=0;d<D;++d) gv[d]=fv[d]-xv[d];
  UPD(1);

  // main loop k=2..49, slots cycle (2,3,4,5,0,1) per 6-period
  for (int kb=2; kb<50; kb+=6){
    ITER(kb+0, 2);
    ITER(kb+1, 3);
    ITER(kb+2, 4);
    ITER(kb+3, 5);
    ITER(kb+4, 0);
    ITER(kb+5, 1);
  }
}

__global__ void final_kernel(const float* __restrict__ d2p, const float* __restrict__ f2p,
                             const float* __restrict__ outk, const float* __restrict__ bf,
                             float* __restrict__ out){
  int b = blockIdx.x*blockDim.x + threadIdx.x;
  float best = 1e8f; int kst = 0;
  for (int k=0;k<NITER;++k){
    float rel = sqrtf(d2p[k]) / (1e-5f + sqrtf(f2p[k]));
    if (rel < best){ best = rel; kst = k; }
  }
  out[b] = outk[(size_t)kst*NB + b] + bf[0];
}

extern "C" void kernel_launch(void* const* d_in, const int* in_sizes, int n_in,
                              void* d_out, int out_size, void* d_ws, size_t ws_size,
                              hipStream_t stream){
  const float* x  = (const float*)d_in[0];
  const float* Wh = (const float*)d_in[1];
  const float* bh = (const float*)d_in[2];
  const float* Wx = (const float*)d_in[3];
  const float* bx = (const float*)d_in[4];
  const float* Wo = (const float*)d_in[5];
  const float* bo = (const float*)d_in[6];
  const float* Wf = (const float*)d_in[7];
  const float* bf = (const float*)d_in[8];
  float* ws  = (float*)d_ws;
  float* out = (float*)d_out;

  hipLaunchKernelGGL(prep_kernel, dim3(1), dim3(256), 0, stream, Wh,bh,Wx,bx,Wo,bo,ws);
  hipLaunchKernelGGL(solver_kernel, dim3(NB/2), dim3(64), 0, stream,
                     x, Wf, ws+WS_WHP, ws+WS_WXP, ws+WS_WOT, ws+WS_BHX, ws+WS_BO,
                     ws+WS_OUTK, ws+WS_D2, ws+WS_F2);
  hipLaunchKernelGGL(final_kernel, dim3(NB/256), dim3(256), 0, stream,
                     ws+WS_D2, ws+WS_F2, ws+WS_OUTK, bf, out);
}

// Round 3
// 3274.719 us; speedup vs baseline: 1.0192x; 1.0192x over previous
//
#include <hip/hip_runtime.h>
#include <hip/hip_fp16.h>

#define S 31
#define D 14
#define H 50
#define NB 16384
#define NITER 48
#define LAMR 1e-4f

// ws float-index layout
#define WS_D2   0      // 48: global sum ||F-X||^2 per iter
#define WS_F2   64     // 48: global sum ||F||^2 per iter
#define WS_WHP  128    // 50x16 fp32 Wh (padded)
#define WS_BHX  928    // 64: bh+bx fp32
#define WS_BO   992    // 16: bo fp32
#define WS_WX2  1024   // 50x8 half2: Wx rows packed (d pairs)
#define WS_WO2  1424   // 14x26 half2: Wo rows packed (h pairs)
#define WS_WF2  1792   // 32x8 half2: Wf per-s slices (row 31 = 0)
#define WS_OUTK 4096   // 48*NB floats

typedef _Float16 f16x2 __attribute__((ext_vector_type(2)));

#if defined(__has_builtin) && __has_builtin(__builtin_amdgcn_rcpf)
#define FRCP(x) __builtin_amdgcn_rcpf(x)
#else
#define FRCP(x) (1.0f/(x))
#endif

#define FDOT2(a,b,c) __builtin_amdgcn_fdot2((a),(b),(c),false)

__device__ __forceinline__ f16x2 pkrtz(float a, float b){
  auto r = __builtin_amdgcn_cvt_pkrtz(a, b);
  return __builtin_bit_cast(f16x2, r);
}
#define PKRTZ(a,b) pkrtz((a),(b))

// triangular index, i<=j, 6x6
#define AIJ(i,j) ((i)*6 - ((i)*((i)+1))/2 + (j))

__device__ __forceinline__ float tfast(float x){
  float e = __expf(x + x);
  return 1.f - 2.f * FRCP(e + 1.f);
}

__device__ __forceinline__ float half_red(float v){
  v += __shfl_xor(v, 1);
  v += __shfl_xor(v, 2);
  v += __shfl_xor(v, 4);
  v += __shfl_xor(v, 8);
  v += __shfl_xor(v, 16);
  return v;   // sum over 32-lane half
}

__global__ void prep_kernel(const float* __restrict__ Wh, const float* __restrict__ bh,
                            const float* __restrict__ Wx, const float* __restrict__ bx,
                            const float* __restrict__ Wo, const float* __restrict__ bo,
                            const float* __restrict__ Wf, float* __restrict__ ws){
  int t = threadIdx.x;                       // 1 block x 256
  for (int i=t;i<128;i+=256) ws[i]=0.f;      // zero norm accumulators
  for (int i=t;i<800;i+=256){
    int h=i>>4, d=i&15;
    ws[WS_WHP+i] = (d<D)? Wh[h*D+d] : 0.f;
  }
  for (int i=t;i<64;i+=256) ws[WS_BHX+i] = (i<H)? bh[i]+bx[i] : 0.f;
  for (int i=t;i<16;i+=256) ws[WS_BO+i]  = (i<D)? bo[i] : 0.f;
  __half2* wx2 = (__half2*)(ws + WS_WX2);
  for (int i=t;i<400;i+=256){
    int h=i>>3, dd=i&7, d0=2*dd, d1=2*dd+1;
    float a=(d0<D)?Wx[h*D+d0]:0.f, b=(d1<D)?Wx[h*D+d1]:0.f;
    wx2[i] = __floats2half2_rn(a,b);
  }
  __half2* wo2 = (__half2*)(ws + WS_WO2);
  for (int i=t;i<364;i+=256){
    int d=i/26, hh=i-26*d, h0=2*hh, h1=2*hh+1;
    float a=(hh<25)?Wo[d*H+h0]:0.f, b=(hh<25)?Wo[d*H+h1]:0.f;
    wo2[i] = __floats2half2_rn(a,b);
  }
  __half2* wf2 = (__half2*)(ws + WS_WF2);
  for (int i=t;i<256;i+=256){
    int s=i>>3, dd=i&7, d0=2*dd, d1=2*dd+1;
    float a=(s<S && d0<D)?Wf[s*D+d0]:0.f, b=(s<S && d1<D)?Wf[s*D+d1]:0.f;
    wf2[i] = __floats2half2_rn(a,b);
  }
}

// f-eval: fvh = tanh( Wo @ tanh(hx + Wx @ xvh) + bo ), fp16 packed, fp32 acc
#define FEVAL() do{ \
  f16x2 thh[25]; \
  _Pragma("unroll") \
  for (int hh_=0; hh_<25; ++hh_){ \
    float a0_ = hxr[2*hh_], b0_ = hxr[2*hh_+1]; \
    _Pragma("unroll") for (int q_=0;q_<7;++q_){ \
      a0_ = FDOT2(xvh[q_], wx2[(2*hh_)*8+q_],   a0_); \
      b0_ = FDOT2(xvh[q_], wx2[(2*hh_+1)*8+q_], b0_); } \
    thh[hh_] = PKRTZ(tfast(a0_), tfast(b0_)); \
  } \
  _Pragma("unroll") \
  for (int dp_=0; dp_<7; ++dp_){ \
    float t0_ = bop[2*dp_], t1_ = bop[2*dp_+1]; \
    float t0b_ = 0.f, t1b_ = 0.f; \
    _Pragma("unroll") for (int hh_=0;hh_<25;hh_+=2){ \
      t0_ = FDOT2(thh[hh_], wo2[(2*dp_)*26+hh_],   t0_); \
      t1_ = FDOT2(thh[hh_], wo2[(2*dp_+1)*26+hh_], t1_); } \
    _Pragma("unroll") for (int hh_=1;hh_<25;hh_+=2){ \
      t0b_ = FDOT2(thh[hh_], wo2[(2*dp_)*26+hh_],   t0b_); \
      t1b_ = FDOT2(thh[hh_], wo2[(2*dp_+1)*26+hh_], t1b_); } \
    fvh[dp_] = PKRTZ(tfast(t0_+t0b_), tfast(t1_+t1b_)); \
  } \
}while(0)

#define ZERO_INACT() do{ \
  if (!act){ \
    _Pragma("unroll") for (int q_=0;q_<7;++q_){ fvh[q_]=zzv; gvh[q_]=zzv; } \
  } \
}while(0)

// push (fvh,gvh) as newest history entry (slot 5), update triangular GG
#define PUSH() do{ \
  float dnew_[5]; \
  _Pragma("unroll") for (int j_=0;j_<5;++j_){ \
    float acc_=0.f; \
    _Pragma("unroll") for (int q_=0;q_<7;++q_) acc_ = FDOT2(gvh[q_], Gh[(j_+1)*7+q_], acc_); \
    dnew_[j_] = half_red(acc_); } \
  d2l=0.f; f2l=0.f; \
  _Pragma("unroll") for (int q_=0;q_<7;++q_){ \
    d2l = FDOT2(gvh[q_], gvh[q_], d2l); \
    f2l = FDOT2(fvh[q_], fvh[q_], f2l); } \
  d2r = half_red(d2l); f2r = half_red(f2l); \
  _Pragma("unroll") for (int j_=0;j_<5;++j_) \
    _Pragma("unroll") for (int q_=0;q_<7;++q_){ \
      Fh[j_*7+q_] = Fh[(j_+1)*7+q_]; Gh[j_*7+q_] = Gh[(j_+1)*7+q_]; } \
  _Pragma("unroll") for (int q_=0;q_<7;++q_){ Fh[35+q_]=fvh[q_]; Gh[35+q_]=gvh[q_]; } \
  _Pragma("unroll") for (int i_=0;i_<5;++i_) \
    _Pragma("unroll") for (int j_=i_;j_<5;++j_) GG[AIJ(i_,j_)] = GG[AIJ(i_+1,j_+1)]; \
  _Pragma("unroll") for (int j_=0;j_<5;++j_) GG[AIJ(j_,5)] = dnew_[j_]; \
  GG[AIJ(5,5)] = d2r; \
}while(0)

__global__ __launch_bounds__(256, 3)
void solver_kernel(const float* __restrict__ x,
                   const float* __restrict__ whp, const float* __restrict__ bhx,
                   const float* __restrict__ bop,
                   const f16x2* __restrict__ wx2, const f16x2* __restrict__ wo2,
                   const f16x2* __restrict__ wf2,
                   float* __restrict__ outk, float* __restrict__ d2p, float* __restrict__ f2p){
  const int tid  = threadIdx.x;
  const int lane = tid & 63;
  const int s    = tid & 31;
  const int elem = blockIdx.x*8 + (tid>>5);
  const bool act = (s < S);

  __shared__ float hx_sh[256*51];   // stride 51: odd -> conflict-free
  float* hxw = hx_sh + tid*51;

  { // prologue: hx[h] = x_s . Wh_h + bh_h + bx_h  (exact fp32)
    float xd[D];
#pragma unroll
    for (int d=0; d<D; ++d) xd[d]=0.f;
    if (act){
      const float* xr = x + ((size_t)elem*S + s)*D;
#pragma unroll
      for (int d=0; d<D; ++d) xd[d]=xr[d];
    }
#pragma unroll 2
    for (int h=0; h<H; ++h){
      float a0 = bhx[h], a1 = 0.f;
#pragma unroll
      for (int d=0; d<D; d+=2){ a0 += xd[d]*whp[h*16+d]; a1 += xd[d+1]*whp[h*16+d+1]; }
      hxw[h] = a0+a1;
    }
  }
  const float* hxr = hxw;
  const f16x2 zzv = {(_Float16)0.f, (_Float16)0.f};

  f16x2 Fh[42], Gh[42], xvh[7], fvh[7], gvh[7];
  float GG[21];
  float d2l, f2l, d2r, f2r;
#pragma unroll
  for (int i=0;i<42;++i){ Fh[i]=zzv; Gh[i]=zzv; }
#pragma unroll
  for (int i=0;i<21;++i) GG[i]=0.f;

  // init entry 0: X0=0, F0=f(0)
#pragma unroll
  for (int q=0;q<7;++q) xvh[q]=zzv;
  FEVAL();
#pragma unroll
  for (int q=0;q<7;++q) gvh[q]=fvh[q]-xvh[q];
  ZERO_INACT();
  PUSH();
  // init entry 1: X1=F0, F1=f(F0)
#pragma unroll
  for (int q=0;q<7;++q) xvh[q]=fvh[q];
  FEVAL();
#pragma unroll
  for (int q=0;q<7;++q) gvh[q]=fvh[q]-xvh[q];
  ZERO_INACT();
  PUSH();

#pragma unroll 1
  for (int kk=2; kk<50; ++kk){
    float A_[21], invd[6], yv[6];
    if (kk >= 6){
#pragma unroll
      for (int i=0;i<6;++i)
#pragma unroll
        for (int j=i;j<6;++j) A_[AIJ(i,j)] = GG[AIJ(i,j)] + ((i==j)?LAMR:0.f);
    } else {
      int lo = 6-kk;
#pragma unroll
      for (int i=0;i<6;++i)
#pragma unroll
        for (int j=i;j<6;++j){
          float v = GG[AIJ(i,j)] + ((i==j)?LAMR:0.f);
          A_[AIJ(i,j)] = (i>=lo)? v : ((i==j)?1e30f:0.f);
        }
    }
#pragma unroll
    for (int i=0;i<6;++i) yv[i]=1.f;
    // symmetric GE (no pivoting; SPD + big-diag pads)
#pragma unroll
    for (int p=0;p<6;++p){
      invd[p] = FRCP(A_[AIJ(p,p)]);
#pragma unroll
      for (int i=p+1;i<6;++i){
        float m = A_[AIJ(p,i)]*invd[p];
#pragma unroll
        for (int j=i;j<6;++j) A_[AIJ(i,j)] -= m*A_[AIJ(p,j)];
        yv[i] -= m*yv[p];
      }
    }
#pragma unroll
    for (int p=5;p>=0;--p){
      float acc=yv[p];
#pragma unroll
      for (int j=p+1;j<6;++j) acc -= A_[AIJ(p,j)]*yv[j];
      yv[p]=acc*invd[p];
    }
    float isum = FRCP(yv[0]+yv[1]+yv[2]+yv[3]+yv[4]+yv[5]);
    // Xk = sum_j alpha_j F_j  (fp16 packed)
#pragma unroll
    for (int q=0;q<7;++q) xvh[q]=zzv;
#pragma unroll
    for (int j=0;j<6;++j){
      _Float16 ah = (_Float16)(yv[j]*isum);
      f16x2 a2 = {ah, ah};
#pragma unroll
      for (int q=0;q<7;++q) xvh[q] += a2*Fh[j*7+q];
    }
    FEVAL();
#pragma unroll
    for (int q=0;q<7;++q) gvh[q]=fvh[q]-xvh[q];
    ZERO_INACT();
    PUSH();
    // projection through Wf for this iterate
    float po=0.f;
    const f16x2* wfr = wf2 + s*8;
#pragma unroll
    for (int q=0;q<7;++q) po = FDOT2(fvh[q], wfr[q], po);
    po = half_red(po);
    float d2w = d2r + __shfl_xor(d2r, 32);
    float f2w = f2r + __shfl_xor(f2r, 32);
    if (lane==0){ atomicAdd(&d2p[kk-2], d2w); atomicAdd(&f2p[kk-2], f2w); }
    if (s==0) outk[(size_t)(kk-2)*NB + elem] = po;
  }
}

__global__ void final_kernel(const float* __restrict__ d2p, const float* __restrict__ f2p,
                             const float* __restrict__ outk, const float* __restrict__ bf,
                             float* __restrict__ out){
  int b = blockIdx.x*blockDim.x + threadIdx.x;
  float best = 1e8f; int kst = 0;
  for (int k=0;k<NITER;++k){
    float rel = sqrtf(d2p[k]) / (1e-5f + sqrtf(f2p[k]));
    if (rel < best){ best = rel; kst = k; }
  }
  out[b] = outk[(size_t)kst*NB + b] + bf[0];
}

extern "C" void kernel_launch(void* const* d_in, const int* in_sizes, int n_in,
                              void* d_out, int out_size, void* d_ws, size_t ws_size,
                              hipStream_t stream){
  const float* x  = (const float*)d_in[0];
  const float* Wh = (const float*)d_in[1];
  const float* bh = (const float*)d_in[2];
  const float* Wx = (const float*)d_in[3];
  const float* bx = (const float*)d_in[4];
  const float* Wo = (const float*)d_in[5];
  const float* bo = (const float*)d_in[6];
  const float* Wf = (const float*)d_in[7];
  const float* bf = (const float*)d_in[8];
  float* ws  = (float*)d_ws;
  float* out = (float*)d_out;

  hipLaunchKernelGGL(prep_kernel, dim3(1), dim3(256), 0, stream, Wh,bh,Wx,bx,Wo,bo,Wf,ws);
  hipLaunchKernelGGL(solver_kernel, dim3(NB/8), dim3(256), 0, stream,
                     x, ws+WS_WHP, ws+WS_BHX, ws+WS_BO,
                     (const f16x2*)(ws+WS_WX2), (const f16x2*)(ws+WS_WO2), (const f16x2*)(ws+WS_WF2),
                     ws+WS_OUTK, ws+WS_D2, ws+WS_F2);
  hipLaunchKernelGGL(final_kernel, dim3(NB/256), dim3(256), 0, stream,
                     ws+WS_D2, ws+WS_F2, ws+WS_OUTK, bf, out);
}